// Round 5
// baseline (448.284 us; speedup 1.0000x reference)
//
#include <hip/hip_runtime.h>
#include <math.h>

#define NATOMS 20000
#define NEDGES 400000
#define EMBD   256
#define NRBF   50
#define NGATE  10
#define FOUT   128
#define APB    4       // atoms per block in k_main
#define OUTERC 5.0f

#define RBF_D    (5.0f/49.0f)
#define RBF_INVD (49.0f/5.0f)
#define RBF_C2   (-0.5f*(49.0f/5.0f)*(49.0f/5.0f)*1.4426950408889634f)
#define PI_OVER_OUTER 0.62831853071795864769f

static __device__ __forceinline__ float softplusf(float x){
    return (x > 15.0f) ? x : log1pf(__expf(x));
}
// round-to-nearest-even bf16, result in HIGH 16 bits
static __device__ __forceinline__ unsigned bfr(float v){
    unsigned u = __float_as_uint(v);
    return (u + 0x7fffu + ((u >> 16) & 1u)) & 0xffff0000u;
}

// ================= k_tab: tables + degree counting =================
// blocks 0..99   : i-side chain per atom type m -> Ti0/Ti1 rows
// blocks 100..199: j-side chain -> Tj0/Tj1 rows
// blocks 200..251: gate/R rows m=0..51 of Y=[Wd@Wdt(50); bd@Wdt; bdt]
// blocks 252..   : edge degree counting
__global__ __launch_bounds__(256) void k_tab(
    const float* __restrict__ emb,
    const float* __restrict__ Wai, const float* __restrict__ bai,
    const float* __restrict__ Waj, const float* __restrict__ baj,
    const float* __restrict__ Wgam,
    const float* __restrict__ Wexp, const float* __restrict__ bexp,
    const float* __restrict__ Wd, const float* __restrict__ Wdt,
    const float* __restrict__ bd, const float* __restrict__ bdt,
    const float* __restrict__ bgam,
    const float* __restrict__ Wg, const float* __restrict__ Wn,
    const int* __restrict__ esrc, int* __restrict__ counts,
    float* __restrict__ Ti0, float* __restrict__ Ti1,
    float* __restrict__ Tj0, float* __restrict__ Tj1,
    float* __restrict__ R0, float* __restrict__ R1,
    float* __restrict__ Qg, float* __restrict__ Qn, float* __restrict__ sv)
{
    const int b = blockIdx.x;
    const int t = threadIdx.x;
    if (b >= 252) {
        int e = (b - 252) * 256 + t;
        if (e < NEDGES) atomicAdd(&counts[esrc[e]], 1);
        return;
    }
    __shared__ float ya[256], za[256];
    if (b < 200) {
        const int side = (b >= 100);
        const int m = side ? b - 100 : b;
        const float* er = emb + m*EMBD;
        const float* W1 = side ? Waj : Wai;
        const float* b1 = side ? baj : bai;
        float s = b1[t];
        #pragma unroll 8
        for (int k = 0; k < EMBD; k++) s += er[k] * W1[k*EMBD + t];
        ya[t] = s;
        __syncthreads();
        const float* G = Wgam + (size_t)(side ? 512 : 256) * EMBD;
        s = 0.f;
        #pragma unroll 8
        for (int k = 0; k < EMBD; k++) s += ya[k] * G[k*EMBD + t];
        za[t] = s;
        __syncthreads();
        const int half = t >> 7, ff = t & 127;
        const float* WX = Wexp + (size_t)half*EMBD*FOUT;
        s = 0.f;
        #pragma unroll 8
        for (int k = 0; k < EMBD; k++) s += za[k] * WX[k*FOUT + ff];
        float* dst = side ? (half ? Tj1 : Tj0) : (half ? Ti1 : Ti0);
        dst[m*FOUT + ff] = s;
        return;
    }
    // gate/R rows
    const int m = b - 200;     // 0..51
    float s;
    if (m < 50) {
        const float* wr = Wd + m*EMBD;
        s = 0.f;
        #pragma unroll 8
        for (int k = 0; k < EMBD; k++) s += wr[k] * Wdt[k*EMBD + t];
    } else if (m == 50) {
        s = 0.f;
        #pragma unroll 8
        for (int k = 0; k < EMBD; k++) s += bd[k] * Wdt[k*EMBD + t];
    } else {
        s = bdt[t];
    }
    ya[t] = s;
    __syncthreads();
    s = 0.f;
    #pragma unroll 8
    for (int k = 0; k < EMBD; k++) s += ya[k] * Wgam[k*EMBD + t];
    if (m == 51) s += bgam[t];
    za[t] = s;
    __syncthreads();
    const int half = t >> 7, ff = t & 127;
    const float* WX = Wexp + (size_t)half*EMBD*FOUT;
    s = 0.f;
    #pragma unroll 8
    for (int k = 0; k < EMBD; k++) s += za[k] * WX[k*FOUT + ff];
    if (m < 50)       (half ? R1 : R0)[m*FOUT + ff] = s;
    else if (m == 50) sv[half*FOUT + ff] = s;
    else              sv[256 + half*FOUT + ff] = s + bexp[half*FOUT + ff];
    if (t < 20) {
        const int tt = t % 10;
        const float* WT = (t < 10) ? Wg : Wn;
        float q = 0.f;
        #pragma unroll 8
        for (int k = 0; k < EMBD; k++) q += ya[k] * WT[k*NGATE + tt];
        if (m < 50) { float* Q = (t < 10) ? Qg : Qn; Q[m*12 + tt] = q; }
        else {
            int off = (m == 50) ? ((t < 10) ? 512 : 532) : ((t < 10) ? 522 : 542);
            sv[off + tt] = q;
            float* Q = (t < 10) ? Qg : Qn; Q[m*12 + tt] = 0.f;   // zero-pad rows 50,51
        }
    }
}

// ================= exclusive scan counts -> cursors =================
__global__ __launch_bounds__(256) void k_scan(const int* __restrict__ counts,
                                              int* __restrict__ cursors)
{
    __shared__ int part[256];
    int t = threadIdx.x;
    const int CH = (NATOMS + 255) / 256;
    int base = t * CH;
    int s = 0;
    for (int i = 0; i < CH; i++) { int idx = base + i; if (idx < NATOMS) s += counts[idx]; }
    part[t] = s;
    __syncthreads();
    for (int d = 1; d < 256; d <<= 1) {
        int v = (t >= d) ? part[t - d] : 0;
        __syncthreads();
        part[t] += v;
        __syncthreads();
    }
    int run = (t == 0) ? 0 : part[t - 1];
    for (int i = 0; i < CH; i++) {
        int idx = base + i;
        if (idx < NATOMS) { cursors[idx] = run; run += counts[idx]; }
    }
}

// ================= k_edge: transform + CSR scatter (AoS 16B + xy word) =================
__global__ __launch_bounds__(256) void k_edge(
    const int* __restrict__ z, const int* __restrict__ esrc, const int* __restrict__ edst,
    const float* __restrict__ ew, const float* __restrict__ evec, const float* __restrict__ noise,
    const float* __restrict__ Qg, const float* __restrict__ Qn, const float* __restrict__ sv,
    int* __restrict__ cursors,
    float4* __restrict__ rec, unsigned* __restrict__ xyS)
{
    __shared__ float qgL[52*12], qnL[52*12];
    __shared__ float nbuf[256*11];
    __shared__ float vbuf[768];
    const int t = threadIdx.x;
    const int e0 = blockIdx.x * 256;

    for (int i = t; i < 52*12; i += 256) { qgL[i] = Qg[i]; qnL[i] = Qn[i]; }
    #pragma unroll
    for (int q = 0; q < 10; q++) {
        int idx = q*256 + t; long long g = (long long)e0*10 + idx;
        if (g < (long long)NEDGES*10) { int r_ = idx/10; nbuf[r_*11 + (idx - r_*10)] = noise[g]; }
    }
    #pragma unroll
    for (int q = 0; q < 3; q++) {
        int idx = q*256 + t; long long g = (long long)e0*3 + idx;
        if (g < (long long)NEDGES*3) vbuf[idx] = evec[g];
    }
    __syncthreads();

    int e = e0 + t;
    if (e >= NEDGES) return;
    float w = ew[e];
    float C = (w < OUTERC) ? 0.5f*(cosf(w*PI_OVER_OUTER) + 1.0f) : 0.0f;
    int iw = (int)(w * RBF_INVD);
    int j0 = (iw - 4) & ~3;
    j0 = max(0, min(40, j0));
    float rW[12];
    #pragma unroll
    for (int k = 0; k < 12; k++) { float tt = w - (j0+k)*RBF_D; rW[k] = exp2f(RBF_C2*tt*tt); }
    float hg[NGATE], hn[NGATE];
    #pragma unroll
    for (int g2 = 0; g2 < NGATE; g2++) { hg[g2] = 0.f; hn[g2] = 0.f; }
    #pragma unroll
    for (int k = 0; k < 12; k++) {
        float rk = rW[k];
        const float* qg = &qgL[(j0+k)*12];
        const float* qn = &qnL[(j0+k)*12];
        float4 ga = *(const float4*)qg; float4 gb = *(const float4*)(qg+4);
        float2 gc = *(const float2*)(qg+8);
        float4 na = *(const float4*)qn; float4 nb = *(const float4*)(qn+4);
        float2 nc = *(const float2*)(qn+8);
        hg[0]=fmaf(rk,ga.x,hg[0]); hg[1]=fmaf(rk,ga.y,hg[1]); hg[2]=fmaf(rk,ga.z,hg[2]); hg[3]=fmaf(rk,ga.w,hg[3]);
        hg[4]=fmaf(rk,gb.x,hg[4]); hg[5]=fmaf(rk,gb.y,hg[5]); hg[6]=fmaf(rk,gb.z,hg[6]); hg[7]=fmaf(rk,gb.w,hg[7]);
        hg[8]=fmaf(rk,gc.x,hg[8]); hg[9]=fmaf(rk,gc.y,hg[9]);
        hn[0]=fmaf(rk,na.x,hn[0]); hn[1]=fmaf(rk,na.y,hn[1]); hn[2]=fmaf(rk,na.z,hn[2]); hn[3]=fmaf(rk,na.w,hn[3]);
        hn[4]=fmaf(rk,nb.x,hn[4]); hn[5]=fmaf(rk,nb.y,hn[5]); hn[6]=fmaf(rk,nb.z,hn[6]); hn[7]=fmaf(rk,nb.w,hn[7]);
        hn[8]=fmaf(rk,nc.x,hn[8]); hn[9]=fmaf(rk,nc.y,hn[9]);
    }
    float H[NGATE];
    #pragma unroll
    for (int g2 = 0; g2 < NGATE; g2++) {
        float gv = C*(hg[g2] + sv[512+g2]) + sv[522+g2];
        float nv = C*(hn[g2] + sv[532+g2]) + sv[542+g2];
        H[g2] = gv + nbuf[t*11 + g2] * softplusf(nv);
    }
    float m1 = -INFINITY, m2 = -INFINITY;
    #pragma unroll
    for (int g2 = 0; g2 < NGATE; g2++) {
        float v = H[g2];
        if (v > m1) { m2 = m1; m1 = v; } else if (v > m2) { m2 = v; }
    }
    float den = 0.f;
    #pragma unroll
    for (int g2 = 0; g2 < NGATE; g2++) den += (H[g2] >= m2) ? __expf(H[g2] - m1) : 0.f;
    float inv = 1.0f / den;
    float g0 = inv;
    float g1 = __expf(m2 - m1) * inv;

    float ex = vbuf[t*3+0], ey = vbuf[t*3+1], ez = vbuf[t*3+2];
    float rn = rsqrtf(ex*ex + ey*ey + ez*ez);
    ex *= rn; ey *= rn; ez *= rn;
    int zd = z[edst[e]];
    int p = atomicAdd(&cursors[esrc[e]], 1);
    rec[p] = make_float4(w,
                         __uint_as_float((bfr(C*g0) >> 16) | bfr(C*g1)),
                         __uint_as_float((bfr(g0) >> 16)   | bfr(g1)),
                         __uint_as_float(bfr(ez) | ((unsigned)j0 << 8) | (unsigned)zd));
    xyS[p] = (bfr(ex) >> 16) | bfr(ey);
}

// ================= main kernel =================
// 256 threads: waves 0-1 = expert 0 (f=tid), waves 2-3 = expert 1 (f=tid-128).
// Atom flush -> barrier-free per-pair LDS slots; one combine at block end.
#define DST(V,KK) acc = fmaf(V, Rc[KK], acc);
#define DOT12(J,RA,RB,RC) { acc = RA.x*Rc[J]; DST(RA.y,(J)+1) DST(RA.z,(J)+2) DST(RA.w,(J)+3) \
  DST(RB.x,(J)+4) DST(RB.y,(J)+5) DST(RB.z,(J)+6) DST(RB.w,(J)+7) \
  DST(RC.x,(J)+8) DST(RC.y,(J)+9) DST(RC.z,(J)+10) DST(RC.w,(J)+11) }

#define PROC(OFF, SXv, TJv, RA, RB, RC, AGv) { \
    int gi = base + i + (OFF); \
    while (gi == nextEnd) { \
        accS[aCur - aBeg][pair][f] = make_float4(accA, accX, accY, accZ); \
        accA = accX = accY = accZ = 0.f; \
        aCur++; \
        if (aCur < aEnd) { nextEnd = cursors[aCur]; dtV = dV + TiT[z[aCur]*FOUT + f]; } \
        else nextEnd = 0x7fffffff; \
    } \
    float acc; \
    switch ((SXv >> 10) & 15) { \
        case 0: DOT12(0,RA,RB,RC)  break; case 1: DOT12(4,RA,RB,RC)  break; \
        case 2: DOT12(8,RA,RB,RC)  break; case 3: DOT12(12,RA,RB,RC) break; \
        case 4: DOT12(16,RA,RB,RC) break; case 5: DOT12(20,RA,RB,RC) break; \
        case 6: DOT12(24,RA,RB,RC) break; case 7: DOT12(28,RA,RB,RC) break; \
        case 8: DOT12(32,RA,RB,RC) break; case 9: DOT12(36,RA,RB,RC) break; \
        default: DOT12(40,RA,RB,RC) break; } \
    float4 sB = *(const float4*)&scal[i+(OFF)][4]; \
    float part_ = fmaf(AGv.x, acc + sV, AGv.y * (dtV + (TJv))); \
    accA += part_; \
    accX = fmaf(sB.x, part_, accX); \
    accY = fmaf(sB.y, part_, accY); \
    accZ = fmaf(sB.z, part_, accZ); \
    int nx = i + (OFF) + 4; nx = (nx < nb4) ? nx : 0; \
    SXv = recI[(size_t)(base + nx)*4 + 3]; \
    TJv = TjT[(SXv & 0xff)*FOUT + f]; \
}

__global__ __launch_bounds__(256, 4) void k_main(
    const int* __restrict__ z, const int* __restrict__ cursors,
    const float4* __restrict__ rec, const unsigned* __restrict__ xyS,
    const float* __restrict__ R0, const float* __restrict__ R1,
    const float* __restrict__ Ti0, const float* __restrict__ Ti1,
    const float* __restrict__ Tj0, const float* __restrict__ Tj1,
    const float* __restrict__ sv, float* __restrict__ out)
{
    __shared__ float  rbuf[256][12];
    __shared__ float  scal[256][8];
    __shared__ float4 accS[APB][2][FOUT];

    const int* recI = (const int*)rec;
    const int tid  = threadIdx.x;
    const int pair = tid >> 7;
    const int f    = tid & 127;

    float Rc[52];
    const float* Rtab = pair ? R1 : R0;
    #pragma unroll
    for (int j = 0; j < NRBF; j++) Rc[j] = Rtab[j*FOUT + f];
    Rc[50] = 0.f; Rc[51] = 0.f;
    const float* TiT = pair ? Ti1 : Ti0;
    const float* TjT = pair ? Tj1 : Tj0;
    const float sV = sv[pair*FOUT + f];
    const float dV = sv[256 + pair*FOUT + f];

    const int aBeg = blockIdx.x * APB;
    const int aEnd = aBeg + APB;
    const int eBeg = (aBeg == 0) ? 0 : cursors[aBeg-1];
    const int eEnd = cursors[aEnd-1];

    int aCur = aBeg;
    int nextEnd = cursors[aCur];
    float dtV = dV + TiT[z[aCur]*FOUT + f];
    float accA=0.f, accX=0.f, accY=0.f, accZ=0.f;

    for (int base = eBeg; base < eEnd; base += 256) {
        const int nb  = min(256, eEnd - base);
        const int nb4 = (nb + 3) & ~3;
        __syncthreads();
        if (tid < nb) {
            int p = base + tid;
            float4 q0 = rec[p];
            unsigned xy = xyS[p];
            float w = q0.x;
            unsigned ab = __float_as_uint(q0.y);
            unsigned gg = __float_as_uint(q0.z);
            unsigned ezd = __float_as_uint(q0.w);
            int j0 = (ezd >> 8) & 0x3f;
            float rr[12];
            #pragma unroll
            for (int k = 0; k < 12; k++) { float tt = w - (j0+k)*RBF_D; rr[k] = exp2f(RBF_C2*tt*tt); }
            float* row = rbuf[tid];
            *(float4*)&row[0] = make_float4(rr[0],rr[1],rr[2],rr[3]);
            *(float4*)&row[4] = make_float4(rr[4],rr[5],rr[6],rr[7]);
            *(float4*)&row[8] = make_float4(rr[8],rr[9],rr[10],rr[11]);
            float* sc = scal[tid];
            *(float4*)&sc[0] = make_float4(__uint_as_float(ab<<16), __uint_as_float(gg<<16),
                                           __uint_as_float(ab & 0xffff0000u), __uint_as_float(gg & 0xffff0000u));
            *(float4*)&sc[4] = make_float4(__uint_as_float(xy<<16), __uint_as_float(xy & 0xffff0000u),
                                           __uint_as_float(ezd & 0xffff0000u), 0.f);
        } else {
            float* row = rbuf[tid];
            *(float4*)&row[0] = make_float4(0,0,0,0);
            *(float4*)&row[4] = make_float4(0,0,0,0);
            *(float4*)&row[8] = make_float4(0,0,0,0);
            float* sc = scal[tid];
            *(float4*)&sc[0] = make_float4(0,0,0,0);
            *(float4*)&sc[4] = make_float4(0,0,0,0);
        }
        __syncthreads();

        int sx0 = recI[(size_t)(base+0)*4 + 3];
        int sx1 = recI[(size_t)(base+1)*4 + 3];
        int sx2 = recI[(size_t)(base+2)*4 + 3];
        int sx3 = recI[(size_t)(base+3)*4 + 3];
        float tj0 = TjT[(sx0 & 0xff)*FOUT + f];
        float tj1 = TjT[(sx1 & 0xff)*FOUT + f];
        float tj2 = TjT[(sx2 & 0xff)*FOUT + f];
        float tj3 = TjT[(sx3 & 0xff)*FOUT + f];

        for (int i = 0; i < nb4; i += 4) {
            const float* rA = rbuf[i];   const float* rB = rbuf[i+1];
            float4 ra0 = *(const float4*)&rA[0], ra1 = *(const float4*)&rA[4], ra2 = *(const float4*)&rA[8];
            float4 rb0 = *(const float4*)&rB[0], rb1 = *(const float4*)&rB[4], rb2 = *(const float4*)&rB[8];
            float2 agA = *(const float2*)&scal[i][pair*2];
            float2 agB = *(const float2*)&scal[i+1][pair*2];
            PROC(0, sx0, tj0, ra0, ra1, ra2, agA)
            PROC(1, sx1, tj1, rb0, rb1, rb2, agB)
            const float* rC = rbuf[i+2]; const float* rD = rbuf[i+3];
            float4 rc0 = *(const float4*)&rC[0], rc1 = *(const float4*)&rC[4], rc2 = *(const float4*)&rC[8];
            float4 rd0 = *(const float4*)&rD[0], rd1 = *(const float4*)&rD[4], rd2 = *(const float4*)&rD[8];
            float2 agC = *(const float2*)&scal[i+2][pair*2];
            float2 agD = *(const float2*)&scal[i+3][pair*2];
            PROC(2, sx2, tj2, rc0, rc1, rc2, agC)
            PROC(3, sx3, tj3, rd0, rd1, rd2, agD)
        }
    }
    // flush remaining owned atoms (incl. empty / trailing)
    while (aCur < aEnd) {
        accS[aCur - aBeg][pair][f] = make_float4(accA, accX, accY, accZ);
        accA = accX = accY = accZ = 0.f;
        aCur++;
    }
    __syncthreads();
    if (tid < FOUT) {
        #pragma unroll
        for (int a2 = 0; a2 < APB; a2++) {
            float4 v0 = accS[a2][0][tid];
            float4 v1 = accS[a2][1][tid];
            int atom = aBeg + a2;
            out[(size_t)atom*FOUT + tid] = v0.x + v1.x;
            float* vb = out + (size_t)NATOMS*FOUT + (size_t)atom*3*FOUT;
            vb[tid]        = v0.y + v1.y;
            vb[FOUT+tid]   = v0.z + v1.z;
            vb[2*FOUT+tid] = v0.w + v1.w;
        }
    }
}

extern "C" void kernel_launch(void* const* d_in, const int* in_sizes, int n_in,
                              void* d_out, int out_size, void* d_ws, size_t ws_size,
                              hipStream_t stream)
{
    const int*   z    = (const int*)d_in[0];
    const int*   ei   = (const int*)d_in[3];
    const int*   esrc = ei;
    const int*   edst = ei + NEDGES;
    const float* ew   = (const float*)d_in[4];
    const float* evec = (const float*)d_in[5];
    const float* nz   = (const float*)d_in[6];
    const float* emb  = (const float*)d_in[7];
    const float* Wd   = (const float*)d_in[8];
    const float* bd   = (const float*)d_in[9];
    const float* Wdt  = (const float*)d_in[10];
    const float* bdt  = (const float*)d_in[11];
    const float* Wai  = (const float*)d_in[12];
    const float* bai  = (const float*)d_in[13];
    const float* Waj  = (const float*)d_in[14];
    const float* baj  = (const float*)d_in[15];
    const float* Wgam = (const float*)d_in[16];
    const float* bgam = (const float*)d_in[17];
    const float* Wg   = (const float*)d_in[18];
    const float* Wn   = (const float*)d_in[19];
    const float* Wexp = (const float*)d_in[20];
    const float* bexp = (const float*)d_in[21];
    float* out = (float*)d_out;

    char* w = (char*)d_ws;
    auto alloc = [&](size_t bytes) -> void* {
        void* p = (void*)w;
        w += (bytes + 255) & ~(size_t)255;
        return p;
    };
    int*   counts  = (int*)alloc(NATOMS * 4);
    int*   cursors = (int*)alloc(NATOMS * 4);
    float* R0  = (float*)alloc(NRBF*FOUT*4);
    float* R1  = (float*)alloc(NRBF*FOUT*4);
    float* Qg  = (float*)alloc(52*12*4);
    float* Qn  = (float*)alloc(52*12*4);
    float* Ti0 = (float*)alloc(100*FOUT*4);
    float* Ti1 = (float*)alloc(100*FOUT*4);
    float* Tj0 = (float*)alloc(100*FOUT*4);
    float* Tj1 = (float*)alloc(100*FOUT*4);
    float* sv  = (float*)alloc(552*4);
    float4*   rec = (float4*)alloc((size_t)NEDGES*16 + 256);  // pad: scalar prefetch over-reads <= +3
    unsigned* xyS = (unsigned*)alloc((size_t)NEDGES*4);

    hipMemsetAsync(counts, 0, NATOMS*4, stream);

    {
        int grid = 252 + (NEDGES + 255) / 256;
        k_tab<<<grid, 256, 0, stream>>>(emb, Wai, bai, Waj, baj, Wgam, Wexp, bexp,
                                        Wd, Wdt, bd, bdt, bgam, Wg, Wn,
                                        esrc, counts,
                                        Ti0, Ti1, Tj0, Tj1, R0, R1, Qg, Qn, sv);
    }
    k_scan<<<1, 256, 0, stream>>>(counts, cursors);
    {
        int grid = (NEDGES + 255) / 256;
        k_edge<<<grid, 256, 0, stream>>>(z, esrc, edst, ew, evec, nz,
                                         Qg, Qn, sv, cursors, rec, xyS);
    }
    {
        int grid = NATOMS / APB;   // 5000
        k_main<<<grid, 256, 0, stream>>>(z, cursors, rec, xyS,
                                         R0, R1, Ti0, Ti1, Tj0, Tj1, sv, out);
    }
}